// Round 1
// baseline (974.302 us; speedup 1.0000x reference)
//
#include <hip/hip_runtime.h>

#define N_NODES 100000
#define N_EDGES 6400000
#define D_IN 256
constexpr float NEG_SLOPE = 0.2f;

// ws layout (floats):
// [0, 2N)   : xl  (source-side transform, [N,2])
// [2N, 4N)  : xr  (target-side transform, [N,2])
// [4N, 6N)  : numer ([N,2])   zeroed each call
// [6N, 7N)  : denom ([N])     zeroed each call
// [7N]      : int flag (1 => edge_index is int64)

// One wave (64 lanes) per node: coalesced float4 row load, butterfly reduce.
__global__ void node_transform(const float* __restrict__ x,
                               const float* __restrict__ Wl, const float* __restrict__ bl,
                               const float* __restrict__ Wr, const float* __restrict__ br,
                               float* __restrict__ xl, float* __restrict__ xr) {
    int wave = (blockIdx.x * blockDim.x + threadIdx.x) >> 6;
    int lane = threadIdx.x & 63;
    if (wave >= N_NODES) return;
    const float4 xv  = *reinterpret_cast<const float4*>(x + (size_t)wave * D_IN + lane * 4);
    const float4 wlA = *reinterpret_cast<const float4*>(Wl + lane * 8);
    const float4 wlB = *reinterpret_cast<const float4*>(Wl + lane * 8 + 4);
    const float4 wrA = *reinterpret_cast<const float4*>(Wr + lane * 8);
    const float4 wrB = *reinterpret_cast<const float4*>(Wr + lane * 8 + 4);
    // Wl row k occupies floats [2k, 2k+1]; lane covers rows 4*lane .. 4*lane+3
    float sl0 = xv.x*wlA.x + xv.y*wlA.z + xv.z*wlB.x + xv.w*wlB.z;
    float sl1 = xv.x*wlA.y + xv.y*wlA.w + xv.z*wlB.y + xv.w*wlB.w;
    float sr0 = xv.x*wrA.x + xv.y*wrA.z + xv.z*wrB.x + xv.w*wrB.z;
    float sr1 = xv.x*wrA.y + xv.y*wrA.w + xv.z*wrB.y + xv.w*wrB.w;
    #pragma unroll
    for (int o = 32; o > 0; o >>= 1) {
        sl0 += __shfl_xor(sl0, o);
        sl1 += __shfl_xor(sl1, o);
        sr0 += __shfl_xor(sr0, o);
        sr1 += __shfl_xor(sr1, o);
    }
    if (lane == 0) {
        xl[2*wave]   = sl0 + bl[0];
        xl[2*wave+1] = sl1 + bl[1];
        xr[2*wave]   = sr0 + br[0];
        xr[2*wave+1] = sr1 + br[1];
    }
}

// Detect whether edge_index is int64 (every odd 32-bit word == 0 since values < 2^17)
// or int32 (odd words are random indices, ~never all zero across 64 samples).
__global__ void detect_dtype(const int* __restrict__ ei32, int* __restrict__ flag) {
    int lane = threadIdx.x;  // 64 threads
    int v = ei32[2 * lane + 1];
    unsigned long long nz = __ballot(v != 0);
    if (lane == 0) *flag = (nz == 0ull) ? 1 : 0;
}

// Single fused edge pass: score -> exp -> atomic accumulate numer/denom per target.
__global__ void edge_pass(const void* __restrict__ ei,
                          const float* __restrict__ eattr,
                          const float* __restrict__ xl, const float* __restrict__ xr,
                          const float* __restrict__ We, const float* __restrict__ att,
                          float* __restrict__ numer, float* __restrict__ denom,
                          const int* __restrict__ flag) {
    const int is64 = *flag;          // uniform
    const float we0 = We[0], we1 = We[1];
    const float a0 = att[0], a1 = att[1];
    const int stride = gridDim.x * blockDim.x;
    for (int e = blockIdx.x * blockDim.x + threadIdx.x; e < N_EDGES; e += stride) {
        int src, tgt;
        if (is64) {
            const long long* p = (const long long*)ei;
            src = (int)p[e];
            tgt = (int)p[N_EDGES + e];
        } else {
            const int* p = (const int*)ei;
            src = p[e];
            tgt = p[N_EDGES + e];
        }
        const float ea = eattr[e];
        const float2 xs = ((const float2*)xl)[src];   // 800 KB table -> L2 hit
        const float2 xt = ((const float2*)xr)[tgt];
        float m0 = xs.x + xt.x + ea * we0;
        float m1 = xs.y + xt.y + ea * we1;
        m0 = m0 > 0.f ? m0 : NEG_SLOPE * m0;
        m1 = m1 > 0.f ? m1 : NEG_SLOPE * m1;
        const float alpha = m0 * a0 + m1 * a1;
        const float ex = __expf(alpha);               // |alpha| bounded ~40, no overflow
        atomicAdd(&denom[tgt], ex);
        atomicAdd(&numer[2*tgt],   ex * xs.x);
        atomicAdd(&numer[2*tgt+1], ex * xs.y);
    }
}

__global__ void finalize(const float* __restrict__ numer, const float* __restrict__ denom,
                         const float* __restrict__ bias, float* __restrict__ out) {
    int i = blockIdx.x * blockDim.x + threadIdx.x;
    if (i >= N_NODES) return;
    const float d = denom[i] + 1e-16f;
    const float2 nm = ((const float2*)numer)[i];
    float2 o;
    o.x = nm.x / d + bias[0];
    o.y = nm.y / d + bias[1];
    ((float2*)out)[i] = o;
}

extern "C" void kernel_launch(void* const* d_in, const int* in_sizes, int n_in,
                              void* d_out, int out_size, void* d_ws, size_t ws_size,
                              hipStream_t stream) {
    const float* x    = (const float*)d_in[0];
    const void*  ei   = d_in[1];
    const float* ea   = (const float*)d_in[2];
    const float* Wl   = (const float*)d_in[3];
    const float* bl   = (const float*)d_in[4];
    const float* Wr   = (const float*)d_in[5];
    const float* br   = (const float*)d_in[6];
    const float* We   = (const float*)d_in[7];
    const float* att  = (const float*)d_in[8];
    const float* bias = (const float*)d_in[9];

    float* ws    = (float*)d_ws;
    float* xl    = ws;
    float* xr    = ws + 2 * N_NODES;
    float* numer = ws + 4 * N_NODES;
    float* denom = ws + 6 * N_NODES;
    int*   flag  = (int*)(ws + 7 * N_NODES);

    // zero the atomic accumulators (numer + denom are contiguous: 3N floats)
    hipMemsetAsync(numer, 0, 3 * N_NODES * sizeof(float), stream);

    node_transform<<<(N_NODES * 64) / 256, 256, 0, stream>>>(x, Wl, bl, Wr, br, xl, xr);
    detect_dtype<<<1, 64, 0, stream>>>((const int*)ei, flag);
    edge_pass<<<2048, 256, 0, stream>>>(ei, ea, xl, xr, We, att, numer, denom, flag);
    finalize<<<(N_NODES + 255) / 256, 256, 0, stream>>>(numer, denom, bias, (float*)d_out);
}